// Round 7
// baseline (267.370 us; speedup 1.0000x reference)
//
#include <hip/hip_runtime.h>

#define N_ 100000
#define E_ 600000
#define IND_ 128
#define OUTD_ 256
#define NT_ (N_/16)        // 6250 row-tiles of 16
#define NB_ 98             // scan blocks of 1024
#define CASTN_ (N_*IND_/2) // 6.4M u32 words of bf16 pairs

typedef __attribute__((ext_vector_type(8))) short bf16x8;
typedef __attribute__((ext_vector_type(4))) float f32x4;
typedef __attribute__((ext_vector_type(2))) unsigned int u32x2;

static __device__ __forceinline__ unsigned f2bf_u(float f){
  union { float f; unsigned u; } v; v.f = f;
  return (v.u + 0x7fffu + ((v.u >> 16) & 1u)) >> 16;   // RNE bf16
}
static __device__ __forceinline__ unsigned pack2(float a, float b){
  return f2bf_u(a) | (f2bf_u(b) << 16);
}
static __device__ __forceinline__ float blo(unsigned u){
  union { unsigned u; float f; } v; v.u = u << 16; return v.f;
}
static __device__ __forceinline__ float bhi(unsigned u){
  union { unsigned u; float f; } v; v.u = u & 0xffff0000u; return v.f;
}

// ---- weight prep (fp32 -> bf16 fragment order) + BN fold + x -> bf16 cast + degree count
__global__ void k_prep(const float* __restrict__ x,
                       const float* __restrict__ W1, const float* __restrict__ W2,
                       const float* __restrict__ Wp, const float* __restrict__ b2,
                       const float* __restrict__ gamma, const float* __restrict__ beta,
                       const float* __restrict__ mean, const float* __restrict__ var,
                       const float* __restrict__ bp,
                       const int* __restrict__ dst, int* __restrict__ deg,
                       unsigned short* __restrict__ W1s, unsigned short* __restrict__ W2s,
                       unsigned short* __restrict__ Wps,
                       float* __restrict__ scale, float* __restrict__ shift,
                       unsigned* __restrict__ xbw)
{
  int gid = blockIdx.x*256 + threadIdx.x;
  if (gid < 16384) {
    const float* W; unsigned short* Ws; int u;
    if (gid < 4096)       { W = W1; Ws = W1s; u = gid; }
    else if (gid < 12288) { W = W2; Ws = W2s; u = gid - 4096; }
    else                  { W = Wp; Ws = Wps; u = gid - 12288; }
    int l  = u & 63;
    int km = (u >> 6) & 1;
    int t  = (u >> 7) & 15;
    int q  = u >> 11;
    int kk = 2*q + km;
    int kb = kk*32 + (l >> 4)*8;
    int c  = 16*t + (l & 15);
    #pragma unroll
    for (int j = 0; j < 8; j++)
      Ws[u*8 + j] = (unsigned short)f2bf_u(W[(size_t)(kb + j)*OUTD_ + c]);
  } else if (gid < 16640) {
    int c = gid - 16384;
    float s = gamma[c] * rsqrtf(var[c] + 1e-5f);
    scale[c] = s;
    shift[c] = (b2[c] - mean[c]) * s + beta[c] + bp[c];
  } else if (gid < 16640 + CASTN_) {
    int ci = gid - 16640;
    float2 v = ((const float2*)x)[ci];
    xbw[ci] = pack2(v.x, v.y);
  } else if (gid < 16640 + CASTN_ + E_) {
    int e = gid - 16640 - CASTN_;
    atomicAdd(&deg[dst[e]], 1);
  }
}

// hierarchical scan pass 1: per-1024-chunk sums
__global__ __launch_bounds__(1024) void k_scan1(const int* __restrict__ deg,
                                                int* __restrict__ bsum, int* __restrict__ offs){
  __shared__ int red[16];
  int tid = threadIdx.x;
  int i = blockIdx.x*1024 + tid;
  int v = (i < N_) ? deg[i] : 0;
  #pragma unroll
  for (int d = 32; d; d >>= 1) v += __shfl_down(v, d);
  if ((tid & 63) == 0) red[tid >> 6] = v;
  __syncthreads();
  if (tid < 16) {
    int s = red[tid];
    #pragma unroll
    for (int d = 8; d; d >>= 1) s += __shfl_down(s, d, 16);
    if (tid == 0) bsum[blockIdx.x] = s;
  }
  if (blockIdx.x == 0 && tid == 0) offs[N_] = E_;
}

// pass 2: each block redundantly scans the 98 block sums + its own chunk
__global__ __launch_bounds__(1024) void k_scan2(const int* __restrict__ deg,
                                                const int* __restrict__ bsum, int* __restrict__ offs){
  __shared__ int bs[128];
  __shared__ int d1[1024];
  int tid = threadIdx.x;
  if (tid < 128) bs[tid] = (tid < NB_) ? bsum[tid] : 0;
  __syncthreads();
  #pragma unroll
  for (int d = 1; d < 128; d <<= 1){
    int v = (tid < 128 && tid >= d) ? bs[tid - d] : 0;
    __syncthreads();
    if (tid < 128) bs[tid] += v;
    __syncthreads();
  }
  int bprefix = (blockIdx.x > 0) ? bs[blockIdx.x - 1] : 0;
  int i = blockIdx.x*1024 + tid;
  int v = (i < N_) ? deg[i] : 0;
  d1[tid] = v;
  __syncthreads();
  #pragma unroll
  for (int d = 1; d < 1024; d <<= 1){
    int t = (tid >= d) ? d1[tid - d] : 0;
    __syncthreads();
    d1[tid] += t;
    __syncthreads();
  }
  if (i < N_) offs[i] = bprefix + d1[tid] - v;
}

__global__ void k_fill(const int* __restrict__ src, const int* __restrict__ dst,
                       const int* __restrict__ offs, int* __restrict__ cur, int* __restrict__ adj){
  int e = blockIdx.x*256 + threadIdx.x;
  if (e < E_) {
    int d = dst[e];
    int p = atomicAdd(&cur[d], 1);
    adj[offs[d] + p] = src[e];
  }
}

// one wave per dst row, bf16 gather (256B/row, 1 dword/lane); 8 rows in flight
__global__ void k_agg(const unsigned* __restrict__ xb32, const int* __restrict__ offs,
                      const int* __restrict__ adj, const float* __restrict__ epsp,
                      unsigned* __restrict__ h0)
{
  int row  = blockIdx.x*4 + (threadIdx.x >> 6);
  int lane = threadIdx.x & 63;
  if (row >= N_) return;
  unsigned xw = xb32[(size_t)row*64 + lane];
  float ax0=0,ay0=0,ax1=0,ay1=0,ax2=0,ay2=0,ax3=0,ay3=0;
  float ax4=0,ay4=0,ax5=0,ay5=0,ax6=0,ay6=0,ax7=0,ay7=0;
  int b = offs[row], e = offs[row+1];
  for (int base = b; base < e; base += 64){
    int cnt = min(64, e - base);
    int idx = adj[base + min(lane, cnt - 1)];
    int j = 0;
    for (; j + 8 <= cnt; j += 8){
      int n0 = __shfl(idx, j+0), n1 = __shfl(idx, j+1);
      int n2 = __shfl(idx, j+2), n3 = __shfl(idx, j+3);
      int n4 = __shfl(idx, j+4), n5 = __shfl(idx, j+5);
      int n6 = __shfl(idx, j+6), n7 = __shfl(idx, j+7);
      unsigned v0 = xb32[(size_t)n0*64 + lane];
      unsigned v1 = xb32[(size_t)n1*64 + lane];
      unsigned v2 = xb32[(size_t)n2*64 + lane];
      unsigned v3 = xb32[(size_t)n3*64 + lane];
      unsigned v4 = xb32[(size_t)n4*64 + lane];
      unsigned v5 = xb32[(size_t)n5*64 + lane];
      unsigned v6 = xb32[(size_t)n6*64 + lane];
      unsigned v7 = xb32[(size_t)n7*64 + lane];
      ax0 += blo(v0); ay0 += bhi(v0);
      ax1 += blo(v1); ay1 += bhi(v1);
      ax2 += blo(v2); ay2 += bhi(v2);
      ax3 += blo(v3); ay3 += bhi(v3);
      ax4 += blo(v4); ay4 += bhi(v4);
      ax5 += blo(v5); ay5 += bhi(v5);
      ax6 += blo(v6); ay6 += bhi(v6);
      ax7 += blo(v7); ay7 += bhi(v7);
    }
    for (; j < cnt; j++){
      int n = __shfl(idx, j);
      unsigned v = xb32[(size_t)n*64 + lane];
      ax0 += blo(v); ay0 += bhi(v);
    }
  }
  float ax = ((ax0+ax1)+(ax2+ax3)) + ((ax4+ax5)+(ax6+ax7));
  float ay = ((ay0+ay1)+(ay2+ay3)) + ((ay4+ay5)+(ay6+ay7));
  float k1 = 1.f + epsp[0];
  h0[(size_t)row*64 + lane] = pack2(fmaf(k1, blo(xw), ax), fmaf(k1, bhi(xw), ay));
}

// Fused MLP: out = BN(relu(h0@W1+b1)@W2) + x@Wp + shift.  h1 never leaves registers.
// 4 waves/block, one 16-row tile per wave; 32KB weight chunks staged with 2 barriers each.
__global__ __launch_bounds__(256) void k_mlp(const unsigned short* __restrict__ h0,
        const unsigned short* __restrict__ xb16,
        const bf16x8* __restrict__ W1s, const float* __restrict__ b1,
        const bf16x8* __restrict__ W2s, const bf16x8* __restrict__ Wps,
        const float* __restrict__ scale, const float* __restrict__ shift,
        float* __restrict__ out)
{
  __shared__ bf16x8 w[2048];                       // 32KB weight chunk
  __shared__ __align__(16) char trans[4][2][1280]; // per-wave 16x(64B+16B pad)
  int tid = threadIdx.x;
  int wv = tid >> 6, lane = tid & 63, g = lane >> 4, r = lane & 15;
  int tile0 = blockIdx.x*4 + wv;
  int tile  = min(tile0, NT_ - 1);

  // B-fragments of h0 (phase B input) and x (phase C proj input)
  const bf16x8* hrow = (const bf16x8*)(h0 + ((size_t)tile*16 + r)*IND_);
  const bf16x8* xrow = (const bf16x8*)(xb16 + ((size_t)tile*16 + r)*IND_);
  bf16x8 B[4], XV[4];
  #pragma unroll
  for (int kk = 0; kk < 4; kk++) B[kk] = hrow[kk*4 + g];
  #pragma unroll
  for (int kk = 0; kk < 4; kk++) XV[kk] = xrow[kk*4 + g];

  f32x4 acc[16];
  #pragma unroll
  for (int t = 0; t < 16; t++) acc[t] = (f32x4){0.f,0.f,0.f,0.f};

  // ---- phase B: acc = h0 @ W1
  for (int q = 0; q < 2; q++){
    __syncthreads();
    #pragma unroll
    for (int i = 0; i < 8; i++) w[tid + i*256] = W1s[q*2048 + tid + i*256];
    __syncthreads();
    #pragma unroll
    for (int km = 0; km < 2; km++){
      bf16x8 Bf = B[2*q + km];
      #pragma unroll
      for (int t = 0; t < 16; t++)
        acc[t] = __builtin_amdgcn_mfma_f32_16x16x32_bf16(w[(t*2+km)*64 + lane], Bf, acc[t], 0,0,0);
    }
  }

  // epilogue B: bias+relu -> bf16 H-fragments via per-wave LDS regroup (stays in registers)
  const float4* b1v = (const float4*)b1;
  bf16x8 H[8];
  #pragma unroll
  for (int kkh = 0; kkh < 8; kkh++){
    char* tr = &trans[wv][kkh & 1][0];
    #pragma unroll
    for (int h = 0; h < 2; h++){
      int t = 2*kkh + h;
      float4 bb = b1v[t*4 + g];
      f32x4 a = acc[t];
      float v0 = fmaxf(a.x + bb.x, 0.f);
      float v1 = fmaxf(a.y + bb.y, 0.f);
      float v2 = fmaxf(a.z + bb.z, 0.f);
      float v3 = fmaxf(a.w + bb.w, 0.f);
      u32x2 dd; dd.x = pack2(v0, v1); dd.y = pack2(v2, v3);
      *(u32x2*)(tr + r*80 + h*32 + g*8) = dd;
    }
    H[kkh] = *(const bf16x8*)(tr + r*80 + g*16);
  }

  #pragma unroll
  for (int t = 0; t < 16; t++) acc[t] = (f32x4){0.f,0.f,0.f,0.f};

  // ---- phase C: acc = h1 @ W2 + x @ Wp
  for (int q = 0; q < 4; q++){
    __syncthreads();
    #pragma unroll
    for (int i = 0; i < 8; i++) w[tid + i*256] = W2s[q*2048 + tid + i*256];
    __syncthreads();
    #pragma unroll
    for (int km = 0; km < 2; km++){
      bf16x8 Bf = H[2*q + km];
      #pragma unroll
      for (int t = 0; t < 16; t++)
        acc[t] = __builtin_amdgcn_mfma_f32_16x16x32_bf16(w[(t*2+km)*64 + lane], Bf, acc[t], 0,0,0);
    }
  }
  for (int q = 0; q < 2; q++){
    __syncthreads();
    #pragma unroll
    for (int i = 0; i < 8; i++) w[tid + i*256] = Wps[q*2048 + tid + i*256];
    __syncthreads();
    #pragma unroll
    for (int km = 0; km < 2; km++){
      bf16x8 Bf = XV[2*q + km];
      #pragma unroll
      for (int t = 0; t < 16; t++)
        acc[t] = __builtin_amdgcn_mfma_f32_16x16x32_bf16(w[(t*2+km)*64 + lane], Bf, acc[t], 0,0,0);
    }
  }

  if (tile0 < NT_){
    const float4* sc = (const float4*)scale;
    const float4* sh = (const float4*)shift;
    #pragma unroll
    for (int t = 0; t < 16; t++){
      float4 s = sc[t*4 + g], b = sh[t*4 + g];
      f32x4 a = acc[t];
      float4 o;
      o.x = fmaf(a.x, s.x, b.x);
      o.y = fmaf(a.y, s.y, b.y);
      o.z = fmaf(a.z, s.z, b.z);
      o.w = fmaf(a.w, s.w, b.w);
      *(float4*)(out + ((size_t)tile*16 + r)*OUTD_ + t*16 + g*4) = o;
    }
  }
}

extern "C" void kernel_launch(void* const* d_in, const int* in_sizes, int n_in,
                              void* d_out, int out_size, void* d_ws, size_t ws_size,
                              hipStream_t stream)
{
  const float* x     = (const float*)d_in[0];
  const int*   ei    = (const int*)d_in[1];     // [2][E]: src then dst
  const float* eps   = (const float*)d_in[2];
  const float* W1    = (const float*)d_in[3];
  const float* b1    = (const float*)d_in[4];
  const float* W2    = (const float*)d_in[5];
  const float* b2    = (const float*)d_in[6];
  const float* gamma = (const float*)d_in[7];
  const float* beta  = (const float*)d_in[8];
  const float* rmean = (const float*)d_in[9];
  const float* rvar  = (const float*)d_in[10];
  const float* Wp    = (const float*)d_in[11];
  const float* bp    = (const float*)d_in[12];
  float* out = (float*)d_out;

  char* ws = (char*)d_ws; size_t off = 0;
  auto carve = [&](size_t b)->char* { char* p = ws + off; off = (off + b + 255) & ~(size_t)255; return p; };
  unsigned*       xbuf  = (unsigned*)carve((size_t)CASTN_*4);   // x as bf16 pairs
  unsigned*       h0    = (unsigned*)carve((size_t)N_*64*4);    // h0 as bf16 pairs
  unsigned short* W1s   = (unsigned short*)carve(4096*16);
  unsigned short* W2s   = (unsigned short*)carve(8192*16);
  unsigned short* Wps   = (unsigned short*)carve(4096*16);
  float*          scale = (float*)carve(256*4);
  float*          shift = (float*)carve(256*4);
  int*            deg   = (int*)carve((size_t)N_*4);
  int*            cur   = (int*)carve((size_t)N_*4);
  int*            offs  = (int*)carve((size_t)(N_+1)*4);
  int*            adj   = (int*)carve((size_t)E_*4);
  int*            bsum  = (int*)carve((size_t)NB_*4);

  hipMemsetAsync(deg, 0, (size_t)N_*4, stream);
  hipMemsetAsync(cur, 0, (size_t)N_*4, stream);

  k_prep <<<(16640 + CASTN_ + E_ + 255)/256, 256, 0, stream>>>(x, W1, W2, Wp, b2, gamma, beta,
                                  rmean, rvar, bp, ei + E_, deg,
                                  W1s, W2s, Wps, scale, shift, xbuf);
  k_scan1<<<NB_, 1024, 0, stream>>>(deg, bsum, offs);
  k_scan2<<<NB_, 1024, 0, stream>>>(deg, bsum, offs);
  k_fill <<<(E_+255)/256, 256, 0, stream>>>(ei, ei + E_, offs, cur, adj);
  k_agg  <<<(N_+3)/4, 256, 0, stream>>>(xbuf, offs, adj, eps, h0);
  k_mlp  <<<(NT_+3)/4, 256, 0, stream>>>((const unsigned short*)h0, (const unsigned short*)xbuf,
                                         (const bf16x8*)W1s, b1, (const bf16x8*)W2s,
                                         (const bf16x8*)Wps, scale, shift, out);
}

// Round 8
// 219.933 us; speedup vs baseline: 1.2157x; 1.2157x over previous
//
#include <hip/hip_runtime.h>

#define N_ 100000
#define E_ 600000
#define IND_ 128
#define OUTD_ 256
#define NT_ (N_/16)        // 6250 row-tiles of 16
#define NB_ 98             // scan blocks of 1024
#define CASTN_ (N_*IND_/2) // 6.4M u32 words of bf16 pairs

typedef __attribute__((ext_vector_type(8))) short bf16x8;
typedef __attribute__((ext_vector_type(4))) float f32x4;
typedef __attribute__((ext_vector_type(2))) unsigned int u32x2;

static __device__ __forceinline__ unsigned f2bf_u(float f){
  union { float f; unsigned u; } v; v.f = f;
  return (v.u + 0x7fffu + ((v.u >> 16) & 1u)) >> 16;   // RNE bf16
}
static __device__ __forceinline__ unsigned pack2(float a, float b){
  return f2bf_u(a) | (f2bf_u(b) << 16);
}
static __device__ __forceinline__ float blo(unsigned u){
  union { unsigned u; float f; } v; v.u = u << 16; return v.f;
}
static __device__ __forceinline__ float bhi(unsigned u){
  union { unsigned u; float f; } v; v.u = u & 0xffff0000u; return v.f;
}
// async global->LDS DMA, 16B per lane per call (wave: 1KB). LDS base must be wave-uniform.
static __device__ __forceinline__ void gload_lds16(const bf16x8* g, bf16x8* l){
  __builtin_amdgcn_global_load_lds((const __attribute__((address_space(1))) void*)g,
                                   (__attribute__((address_space(3))) void*)l, 16, 0, 0);
}

// ---- weight prep (fp32 -> bf16 fragment order) + BN fold + x -> bf16 cast + degree count
__global__ void k_prep(const float* __restrict__ x,
                       const float* __restrict__ W1, const float* __restrict__ W2,
                       const float* __restrict__ Wp, const float* __restrict__ b2,
                       const float* __restrict__ gamma, const float* __restrict__ beta,
                       const float* __restrict__ mean, const float* __restrict__ var,
                       const float* __restrict__ bp,
                       const int* __restrict__ dst, int* __restrict__ deg,
                       unsigned short* __restrict__ W1s, unsigned short* __restrict__ W2s,
                       unsigned short* __restrict__ Wps,
                       float* __restrict__ scale, float* __restrict__ shift,
                       unsigned* __restrict__ xbw)
{
  int gid = blockIdx.x*256 + threadIdx.x;
  if (gid < 16384) {
    const float* W; unsigned short* Ws; int u;
    if (gid < 4096)       { W = W1; Ws = W1s; u = gid; }
    else if (gid < 12288) { W = W2; Ws = W2s; u = gid - 4096; }
    else                  { W = Wp; Ws = Wps; u = gid - 12288; }
    int l  = u & 63;
    int km = (u >> 6) & 1;
    int t  = (u >> 7) & 15;
    int q  = u >> 11;
    int kk = 2*q + km;
    int kb = kk*32 + (l >> 4)*8;
    int c  = 16*t + (l & 15);
    #pragma unroll
    for (int j = 0; j < 8; j++)
      Ws[u*8 + j] = (unsigned short)f2bf_u(W[(size_t)(kb + j)*OUTD_ + c]);
  } else if (gid < 16640) {
    int c = gid - 16384;
    float s = gamma[c] * rsqrtf(var[c] + 1e-5f);
    scale[c] = s;
    shift[c] = (b2[c] - mean[c]) * s + beta[c] + bp[c];
  } else if (gid < 16640 + CASTN_) {
    int ci = gid - 16640;
    float2 v = ((const float2*)x)[ci];
    xbw[ci] = pack2(v.x, v.y);
  } else if (gid < 16640 + CASTN_ + E_) {
    int e = gid - 16640 - CASTN_;
    atomicAdd(&deg[dst[e]], 1);
  }
}

// hierarchical scan pass 1: per-1024-chunk sums
__global__ __launch_bounds__(1024) void k_scan1(const int* __restrict__ deg,
                                                int* __restrict__ bsum, int* __restrict__ offs){
  __shared__ int red[16];
  int tid = threadIdx.x;
  int i = blockIdx.x*1024 + tid;
  int v = (i < N_) ? deg[i] : 0;
  #pragma unroll
  for (int d = 32; d; d >>= 1) v += __shfl_down(v, d);
  if ((tid & 63) == 0) red[tid >> 6] = v;
  __syncthreads();
  if (tid < 16) {
    int s = red[tid];
    #pragma unroll
    for (int d = 8; d; d >>= 1) s += __shfl_down(s, d, 16);
    if (tid == 0) bsum[blockIdx.x] = s;
  }
  if (blockIdx.x == 0 && tid == 0) offs[N_] = E_;
}

// pass 2: each block redundantly scans the 98 block sums + its own chunk
__global__ __launch_bounds__(1024) void k_scan2(const int* __restrict__ deg,
                                                const int* __restrict__ bsum, int* __restrict__ offs){
  __shared__ int bs[128];
  __shared__ int d1[1024];
  int tid = threadIdx.x;
  if (tid < 128) bs[tid] = (tid < NB_) ? bsum[tid] : 0;
  __syncthreads();
  #pragma unroll
  for (int d = 1; d < 128; d <<= 1){
    int v = (tid < 128 && tid >= d) ? bs[tid - d] : 0;
    __syncthreads();
    if (tid < 128) bs[tid] += v;
    __syncthreads();
  }
  int bprefix = (blockIdx.x > 0) ? bs[blockIdx.x - 1] : 0;
  int i = blockIdx.x*1024 + tid;
  int v = (i < N_) ? deg[i] : 0;
  d1[tid] = v;
  __syncthreads();
  #pragma unroll
  for (int d = 1; d < 1024; d <<= 1){
    int t = (tid >= d) ? d1[tid - d] : 0;
    __syncthreads();
    d1[tid] += t;
    __syncthreads();
  }
  if (i < N_) offs[i] = bprefix + d1[tid] - v;
}

__global__ void k_fill(const int* __restrict__ src, const int* __restrict__ dst,
                       const int* __restrict__ offs, int* __restrict__ cur, int* __restrict__ adj){
  int e = blockIdx.x*256 + threadIdx.x;
  if (e < E_) {
    int d = dst[e];
    int p = atomicAdd(&cur[d], 1);
    adj[offs[d] + p] = src[e];
  }
}

// one wave per dst row, bf16 gather (256B/row, 1 dword/lane); 8 rows in flight
__global__ void k_agg(const unsigned* __restrict__ xb32, const int* __restrict__ offs,
                      const int* __restrict__ adj, const float* __restrict__ epsp,
                      unsigned* __restrict__ h0)
{
  int row  = blockIdx.x*4 + (threadIdx.x >> 6);
  int lane = threadIdx.x & 63;
  if (row >= N_) return;
  unsigned xw = xb32[(size_t)row*64 + lane];
  float ax0=0,ay0=0,ax1=0,ay1=0,ax2=0,ay2=0,ax3=0,ay3=0;
  float ax4=0,ay4=0,ax5=0,ay5=0,ax6=0,ay6=0,ax7=0,ay7=0;
  int b = offs[row], e = offs[row+1];
  for (int base = b; base < e; base += 64){
    int cnt = min(64, e - base);
    int idx = adj[base + min(lane, cnt - 1)];
    int j = 0;
    for (; j + 8 <= cnt; j += 8){
      int n0 = __shfl(idx, j+0), n1 = __shfl(idx, j+1);
      int n2 = __shfl(idx, j+2), n3 = __shfl(idx, j+3);
      int n4 = __shfl(idx, j+4), n5 = __shfl(idx, j+5);
      int n6 = __shfl(idx, j+6), n7 = __shfl(idx, j+7);
      unsigned v0 = xb32[(size_t)n0*64 + lane];
      unsigned v1 = xb32[(size_t)n1*64 + lane];
      unsigned v2 = xb32[(size_t)n2*64 + lane];
      unsigned v3 = xb32[(size_t)n3*64 + lane];
      unsigned v4 = xb32[(size_t)n4*64 + lane];
      unsigned v5 = xb32[(size_t)n5*64 + lane];
      unsigned v6 = xb32[(size_t)n6*64 + lane];
      unsigned v7 = xb32[(size_t)n7*64 + lane];
      ax0 += blo(v0); ay0 += bhi(v0);
      ax1 += blo(v1); ay1 += bhi(v1);
      ax2 += blo(v2); ay2 += bhi(v2);
      ax3 += blo(v3); ay3 += bhi(v3);
      ax4 += blo(v4); ay4 += bhi(v4);
      ax5 += blo(v5); ay5 += bhi(v5);
      ax6 += blo(v6); ay6 += bhi(v6);
      ax7 += blo(v7); ay7 += bhi(v7);
    }
    for (; j < cnt; j++){
      int n = __shfl(idx, j);
      unsigned v = xb32[(size_t)n*64 + lane];
      ax0 += blo(v); ay0 += bhi(v);
    }
  }
  float ax = ((ax0+ax1)+(ax2+ax3)) + ((ax4+ax5)+(ax6+ax7));
  float ay = ((ay0+ay1)+(ay2+ay3)) + ((ay4+ay5)+(ay6+ay7));
  float k1 = 1.f + epsp[0];
  h0[(size_t)row*64 + lane] = pack2(fmaf(k1, blo(xw), ax), fmaf(k1, bhi(xw), ay));
}

// Fused MLP: out = BN(relu(h0@W1+b1)@W2) + x@Wp + shift.  h1 never leaves registers.
// Weight chunks staged via async global_load_lds (16B/lane, no VGPR round-trip).
__global__ __launch_bounds__(256) void k_mlp(const unsigned short* __restrict__ h0,
        const unsigned short* __restrict__ xb16,
        const bf16x8* __restrict__ W1s, const float* __restrict__ b1,
        const bf16x8* __restrict__ W2s, const bf16x8* __restrict__ Wps,
        const float* __restrict__ scale, const float* __restrict__ shift,
        float* __restrict__ out)
{
  __shared__ bf16x8 w[2048];                       // 32KB weight chunk
  __shared__ __align__(16) char trans[4][2][1280]; // per-wave 16x(64B+16B pad)
  int tid = threadIdx.x;
  int wv = tid >> 6, lane = tid & 63, g = lane >> 4, r = lane & 15;
  int tile0 = blockIdx.x*4 + wv;
  int tile  = min(tile0, NT_ - 1);

  // B-fragments of h0 (phase B input) and x (phase C proj input)
  const bf16x8* hrow = (const bf16x8*)(h0 + ((size_t)tile*16 + r)*IND_);
  const bf16x8* xrow = (const bf16x8*)(xb16 + ((size_t)tile*16 + r)*IND_);
  bf16x8 B[4], XV[4];
  #pragma unroll
  for (int kk = 0; kk < 4; kk++) B[kk] = hrow[kk*4 + g];
  #pragma unroll
  for (int kk = 0; kk < 4; kk++) XV[kk] = xrow[kk*4 + g];

  f32x4 acc[16];
  #pragma unroll
  for (int t = 0; t < 16; t++) acc[t] = (f32x4){0.f,0.f,0.f,0.f};

  // ---- phase B: acc = h0 @ W1
  for (int q = 0; q < 2; q++){
    __syncthreads();
    #pragma unroll
    for (int i = 0; i < 8; i++)
      gload_lds16(&W1s[q*2048 + i*256 + wv*64 + lane], &w[i*256 + wv*64]);
    __syncthreads();
    #pragma unroll
    for (int km = 0; km < 2; km++){
      bf16x8 Bf = B[2*q + km];
      #pragma unroll
      for (int t = 0; t < 16; t++)
        acc[t] = __builtin_amdgcn_mfma_f32_16x16x32_bf16(w[(t*2+km)*64 + lane], Bf, acc[t], 0,0,0);
    }
  }

  // epilogue B: bias+relu -> bf16 H-fragments via per-wave LDS regroup (stays in registers)
  const float4* b1v = (const float4*)b1;
  bf16x8 H[8];
  #pragma unroll
  for (int kkh = 0; kkh < 8; kkh++){
    char* tr = &trans[wv][kkh & 1][0];
    #pragma unroll
    for (int h = 0; h < 2; h++){
      int t = 2*kkh + h;
      float4 bb = b1v[t*4 + g];
      f32x4 a = acc[t];
      float v0 = fmaxf(a.x + bb.x, 0.f);
      float v1 = fmaxf(a.y + bb.y, 0.f);
      float v2 = fmaxf(a.z + bb.z, 0.f);
      float v3 = fmaxf(a.w + bb.w, 0.f);
      u32x2 dd; dd.x = pack2(v0, v1); dd.y = pack2(v2, v3);
      *(u32x2*)(tr + r*80 + h*32 + g*8) = dd;
    }
    H[kkh] = *(const bf16x8*)(tr + r*80 + g*16);
  }

  #pragma unroll
  for (int t = 0; t < 16; t++) acc[t] = (f32x4){0.f,0.f,0.f,0.f};

  // ---- phase C: acc = h1 @ W2 + x @ Wp
  for (int q = 0; q < 4; q++){
    __syncthreads();
    #pragma unroll
    for (int i = 0; i < 8; i++)
      gload_lds16(&W2s[q*2048 + i*256 + wv*64 + lane], &w[i*256 + wv*64]);
    __syncthreads();
    #pragma unroll
    for (int km = 0; km < 2; km++){
      bf16x8 Bf = H[2*q + km];
      #pragma unroll
      for (int t = 0; t < 16; t++)
        acc[t] = __builtin_amdgcn_mfma_f32_16x16x32_bf16(w[(t*2+km)*64 + lane], Bf, acc[t], 0,0,0);
    }
  }
  for (int q = 0; q < 2; q++){
    __syncthreads();
    #pragma unroll
    for (int i = 0; i < 8; i++)
      gload_lds16(&Wps[q*2048 + i*256 + wv*64 + lane], &w[i*256 + wv*64]);
    __syncthreads();
    #pragma unroll
    for (int km = 0; km < 2; km++){
      bf16x8 Bf = XV[2*q + km];
      #pragma unroll
      for (int t = 0; t < 16; t++)
        acc[t] = __builtin_amdgcn_mfma_f32_16x16x32_bf16(w[(t*2+km)*64 + lane], Bf, acc[t], 0,0,0);
    }
  }

  if (tile0 < NT_){
    const float4* sc = (const float4*)scale;
    const float4* sh = (const float4*)shift;
    #pragma unroll
    for (int t = 0; t < 16; t++){
      float4 s = sc[t*4 + g], b = sh[t*4 + g];
      f32x4 a = acc[t];
      float4 o;
      o.x = fmaf(a.x, s.x, b.x);
      o.y = fmaf(a.y, s.y, b.y);
      o.z = fmaf(a.z, s.z, b.z);
      o.w = fmaf(a.w, s.w, b.w);
      *(float4*)(out + ((size_t)tile*16 + r)*OUTD_ + t*16 + g*4) = o;
    }
  }
}

extern "C" void kernel_launch(void* const* d_in, const int* in_sizes, int n_in,
                              void* d_out, int out_size, void* d_ws, size_t ws_size,
                              hipStream_t stream)
{
  const float* x     = (const float*)d_in[0];
  const int*   ei    = (const int*)d_in[1];     // [2][E]: src then dst
  const float* eps   = (const float*)d_in[2];
  const float* W1    = (const float*)d_in[3];
  const float* b1    = (const float*)d_in[4];
  const float* W2    = (const float*)d_in[5];
  const float* b2    = (const float*)d_in[6];
  const float* gamma = (const float*)d_in[7];
  const float* beta  = (const float*)d_in[8];
  const float* rmean = (const float*)d_in[9];
  const float* rvar  = (const float*)d_in[10];
  const float* Wp    = (const float*)d_in[11];
  const float* bp    = (const float*)d_in[12];
  float* out = (float*)d_out;

  char* ws = (char*)d_ws; size_t off = 0;
  auto carve = [&](size_t b)->char* { char* p = ws + off; off = (off + b + 255) & ~(size_t)255; return p; };
  unsigned*       xbuf  = (unsigned*)carve((size_t)CASTN_*4);   // x as bf16 pairs
  unsigned*       h0    = (unsigned*)carve((size_t)N_*64*4);    // h0 as bf16 pairs
  unsigned short* W1s   = (unsigned short*)carve(4096*16);
  unsigned short* W2s   = (unsigned short*)carve(8192*16);
  unsigned short* Wps   = (unsigned short*)carve(4096*16);
  float*          scale = (float*)carve(256*4);
  float*          shift = (float*)carve(256*4);
  int*            deg   = (int*)carve((size_t)N_*4);
  int*            cur   = (int*)carve((size_t)N_*4);
  int*            offs  = (int*)carve((size_t)(N_+1)*4);
  int*            adj   = (int*)carve((size_t)E_*4);
  int*            bsum  = (int*)carve((size_t)NB_*4);

  hipMemsetAsync(deg, 0, (size_t)N_*4, stream);
  hipMemsetAsync(cur, 0, (size_t)N_*4, stream);

  k_prep <<<(16640 + CASTN_ + E_ + 255)/256, 256, 0, stream>>>(x, W1, W2, Wp, b2, gamma, beta,
                                  rmean, rvar, bp, ei + E_, deg,
                                  W1s, W2s, Wps, scale, shift, xbuf);
  k_scan1<<<NB_, 1024, 0, stream>>>(deg, bsum, offs);
  k_scan2<<<NB_, 1024, 0, stream>>>(deg, bsum, offs);
  k_fill <<<(E_+255)/256, 256, 0, stream>>>(ei, ei + E_, offs, cur, adj);
  k_agg  <<<(N_+3)/4, 256, 0, stream>>>(xbuf, offs, adj, eps, h0);
  k_mlp  <<<(NT_+3)/4, 256, 0, stream>>>((const unsigned short*)h0, (const unsigned short*)xbuf,
                                         (const bf16x8*)W1s, b1, (const bf16x8*)W2s,
                                         (const bf16x8*)Wps, scale, shift, out);
}

// Round 9
// 195.968 us; speedup vs baseline: 1.3644x; 1.1223x over previous
//
#include <hip/hip_runtime.h>

#define N_ 100000
#define E_ 600000
#define IND_ 128
#define OUTD_ 256
#define NT_ (N_/16)        // 6250 row-tiles of 16
#define NB_ 98             // scan blocks of 1024
#define CASTN_ (N_*IND_/2) // 6.4M u32 words of bf16 pairs

typedef __attribute__((ext_vector_type(8))) short bf16x8;
typedef __attribute__((ext_vector_type(4))) float f32x4;
typedef __attribute__((ext_vector_type(2))) unsigned int u32x2;

static __device__ __forceinline__ unsigned f2bf_u(float f){
  union { float f; unsigned u; } v; v.f = f;
  return (v.u + 0x7fffu + ((v.u >> 16) & 1u)) >> 16;   // RNE bf16
}
static __device__ __forceinline__ unsigned pack2(float a, float b){
  return f2bf_u(a) | (f2bf_u(b) << 16);
}
static __device__ __forceinline__ float blo(unsigned u){
  union { unsigned u; float f; } v; v.u = u << 16; return v.f;
}
static __device__ __forceinline__ float bhi(unsigned u){
  union { unsigned u; float f; } v; v.u = u & 0xffff0000u; return v.f;
}
// async global->LDS DMA, 16B per lane per call (wave: 1KB). LDS base must be wave-uniform.
static __device__ __forceinline__ void gload_lds16(const bf16x8* g, bf16x8* l){
  __builtin_amdgcn_global_load_lds((const __attribute__((address_space(1))) void*)g,
                                   (__attribute__((address_space(3))) void*)l, 16, 0, 0);
}

// ---- weight prep (fp32 -> bf16 fragment order) + BN fold + x -> bf16 cast + degree count
__global__ void k_prep(const float* __restrict__ x,
                       const float* __restrict__ W1, const float* __restrict__ W2,
                       const float* __restrict__ Wp, const float* __restrict__ b2,
                       const float* __restrict__ gamma, const float* __restrict__ beta,
                       const float* __restrict__ mean, const float* __restrict__ var,
                       const float* __restrict__ bp,
                       const int* __restrict__ dst, int* __restrict__ deg,
                       unsigned short* __restrict__ W1s, unsigned short* __restrict__ W2s,
                       unsigned short* __restrict__ Wps,
                       float* __restrict__ scale, float* __restrict__ shift,
                       unsigned* __restrict__ xbw)
{
  int gid = blockIdx.x*256 + threadIdx.x;
  if (gid < 16384) {
    const float* W; unsigned short* Ws; int u;
    if (gid < 4096)       { W = W1; Ws = W1s; u = gid; }
    else if (gid < 12288) { W = W2; Ws = W2s; u = gid - 4096; }
    else                  { W = Wp; Ws = Wps; u = gid - 12288; }
    int l  = u & 63;
    int km = (u >> 6) & 1;
    int t  = (u >> 7) & 15;
    int q  = u >> 11;
    int kk = 2*q + km;
    int kb = kk*32 + (l >> 4)*8;
    int c  = 16*t + (l & 15);
    #pragma unroll
    for (int j = 0; j < 8; j++)
      Ws[u*8 + j] = (unsigned short)f2bf_u(W[(size_t)(kb + j)*OUTD_ + c]);
  } else if (gid < 16640) {
    int c = gid - 16384;
    float s = gamma[c] * rsqrtf(var[c] + 1e-5f);
    scale[c] = s;
    shift[c] = (b2[c] - mean[c]) * s + beta[c] + bp[c];
  } else if (gid < 16640 + CASTN_) {
    int ci = gid - 16640;
    float2 v = ((const float2*)x)[ci];
    xbw[ci] = pack2(v.x, v.y);
  } else if (gid < 16640 + CASTN_ + E_) {
    int e = gid - 16640 - CASTN_;
    atomicAdd(&deg[dst[e]], 1);
  }
}

// hierarchical scan pass 1: per-1024-chunk sums
__global__ __launch_bounds__(1024) void k_scan1(const int* __restrict__ deg,
                                                int* __restrict__ bsum, int* __restrict__ offs){
  __shared__ int red[16];
  int tid = threadIdx.x;
  int i = blockIdx.x*1024 + tid;
  int v = (i < N_) ? deg[i] : 0;
  #pragma unroll
  for (int d = 32; d; d >>= 1) v += __shfl_down(v, d);
  if ((tid & 63) == 0) red[tid >> 6] = v;
  __syncthreads();
  if (tid < 16) {
    int s = red[tid];
    #pragma unroll
    for (int d = 8; d; d >>= 1) s += __shfl_down(s, d, 16);
    if (tid == 0) bsum[blockIdx.x] = s;
  }
  if (blockIdx.x == 0 && tid == 0) offs[N_] = E_;
}

// pass 2: each block redundantly scans the 98 block sums + its own chunk
__global__ __launch_bounds__(1024) void k_scan2(const int* __restrict__ deg,
                                                const int* __restrict__ bsum, int* __restrict__ offs){
  __shared__ int bs[128];
  __shared__ int d1[1024];
  int tid = threadIdx.x;
  if (tid < 128) bs[tid] = (tid < NB_) ? bsum[tid] : 0;
  __syncthreads();
  #pragma unroll
  for (int d = 1; d < 128; d <<= 1){
    int v = (tid < 128 && tid >= d) ? bs[tid - d] : 0;
    __syncthreads();
    if (tid < 128) bs[tid] += v;
    __syncthreads();
  }
  int bprefix = (blockIdx.x > 0) ? bs[blockIdx.x - 1] : 0;
  int i = blockIdx.x*1024 + tid;
  int v = (i < N_) ? deg[i] : 0;
  d1[tid] = v;
  __syncthreads();
  #pragma unroll
  for (int d = 1; d < 1024; d <<= 1){
    int t = (tid >= d) ? d1[tid - d] : 0;
    __syncthreads();
    d1[tid] += t;
    __syncthreads();
  }
  if (i < N_) offs[i] = bprefix + d1[tid] - v;
}

__global__ void k_fill(const int* __restrict__ src, const int* __restrict__ dst,
                       const int* __restrict__ offs, int* __restrict__ cur, int* __restrict__ adj){
  int e = blockIdx.x*256 + threadIdx.x;
  if (e < E_) {
    int d = dst[e];
    int p = atomicAdd(&cur[d], 1);
    adj[offs[d] + p] = src[e];
  }
}

// one wave per dst row, bf16 gather (256B/row, 1 dword/lane); 8 rows in flight
__global__ void k_agg(const unsigned* __restrict__ xb32, const int* __restrict__ offs,
                      const int* __restrict__ adj, const float* __restrict__ epsp,
                      unsigned* __restrict__ h0)
{
  int row  = blockIdx.x*4 + (threadIdx.x >> 6);
  int lane = threadIdx.x & 63;
  if (row >= N_) return;
  unsigned xw = xb32[(size_t)row*64 + lane];
  float ax0=0,ay0=0,ax1=0,ay1=0,ax2=0,ay2=0,ax3=0,ay3=0;
  float ax4=0,ay4=0,ax5=0,ay5=0,ax6=0,ay6=0,ax7=0,ay7=0;
  int b = offs[row], e = offs[row+1];
  for (int base = b; base < e; base += 64){
    int cnt = min(64, e - base);
    int idx = adj[base + min(lane, cnt - 1)];
    int j = 0;
    for (; j + 8 <= cnt; j += 8){
      int n0 = __shfl(idx, j+0), n1 = __shfl(idx, j+1);
      int n2 = __shfl(idx, j+2), n3 = __shfl(idx, j+3);
      int n4 = __shfl(idx, j+4), n5 = __shfl(idx, j+5);
      int n6 = __shfl(idx, j+6), n7 = __shfl(idx, j+7);
      unsigned v0 = xb32[(size_t)n0*64 + lane];
      unsigned v1 = xb32[(size_t)n1*64 + lane];
      unsigned v2 = xb32[(size_t)n2*64 + lane];
      unsigned v3 = xb32[(size_t)n3*64 + lane];
      unsigned v4 = xb32[(size_t)n4*64 + lane];
      unsigned v5 = xb32[(size_t)n5*64 + lane];
      unsigned v6 = xb32[(size_t)n6*64 + lane];
      unsigned v7 = xb32[(size_t)n7*64 + lane];
      ax0 += blo(v0); ay0 += bhi(v0);
      ax1 += blo(v1); ay1 += bhi(v1);
      ax2 += blo(v2); ay2 += bhi(v2);
      ax3 += blo(v3); ay3 += bhi(v3);
      ax4 += blo(v4); ay4 += bhi(v4);
      ax5 += blo(v5); ay5 += bhi(v5);
      ax6 += blo(v6); ay6 += bhi(v6);
      ax7 += blo(v7); ay7 += bhi(v7);
    }
    for (; j < cnt; j++){
      int n = __shfl(idx, j);
      unsigned v = xb32[(size_t)n*64 + lane];
      ax0 += blo(v); ay0 += bhi(v);
    }
  }
  float ax = ((ax0+ax1)+(ax2+ax3)) + ((ax4+ax5)+(ax6+ax7));
  float ay = ((ay0+ay1)+(ay2+ay3)) + ((ay4+ay5)+(ay6+ay7));
  float k1 = 1.f + epsp[0];
  h0[(size_t)row*64 + lane] = pack2(fmaf(k1, blo(xw), ax), fmaf(k1, bhi(xw), ay));
}

// Fused MLP: out = BN(relu(h0@W1+b1)@W2) + x@Wp + shift.  h1 never leaves registers.
// Double-buffered async weight staging: STAGE(next) issued before MFMA(current),
// one __syncthreads per phase (implicit vmcnt(0) is the drain). 8 phases total.
__global__ __launch_bounds__(256) void k_mlp(const unsigned short* __restrict__ h0,
        const unsigned short* __restrict__ xb16,
        const bf16x8* __restrict__ W1s, const float* __restrict__ b1,
        const bf16x8* __restrict__ W2s, const bf16x8* __restrict__ Wps,
        const float* __restrict__ scale, const float* __restrict__ shift,
        float* __restrict__ out)
{
  __shared__ bf16x8 w[2][2048];                    // 2 x 32KB weight chunks (double buffer)
  __shared__ __align__(16) char trans[4][2][1280]; // per-wave 16x(64B+16B pad)
  int tid = threadIdx.x;
  int wv = tid >> 6, lane = tid & 63, g = lane >> 4, r = lane & 15;
  int tile0 = blockIdx.x*4 + wv;
  int tile  = min(tile0, NT_ - 1);

  // B-fragments of h0 (phase B input) and x (phase C proj input)
  const bf16x8* hrow = (const bf16x8*)(h0 + ((size_t)tile*16 + r)*IND_);
  const bf16x8* xrow = (const bf16x8*)(xb16 + ((size_t)tile*16 + r)*IND_);
  bf16x8 B[4], XV[4];
  #pragma unroll
  for (int kk = 0; kk < 4; kk++) B[kk] = hrow[kk*4 + g];
  #pragma unroll
  for (int kk = 0; kk < 4; kk++) XV[kk] = xrow[kk*4 + g];

  auto STAGE = [&](int buf, const bf16x8* src){
    #pragma unroll
    for (int i = 0; i < 8; i++)
      gload_lds16(&src[i*256 + wv*64 + lane], &w[buf][i*256 + wv*64]);
  };
  f32x4 acc[16];
  auto MF = [&](int buf, bf16x8 f0, bf16x8 f1){
    #pragma unroll
    for (int t = 0; t < 16; t++)
      acc[t] = __builtin_amdgcn_mfma_f32_16x16x32_bf16(w[buf][(t*2+0)*64 + lane], f0, acc[t], 0,0,0);
    #pragma unroll
    for (int t = 0; t < 16; t++)
      acc[t] = __builtin_amdgcn_mfma_f32_16x16x32_bf16(w[buf][(t*2+1)*64 + lane], f1, acc[t], 0,0,0);
  };
  #pragma unroll
  for (int t = 0; t < 16; t++) acc[t] = (f32x4){0.f,0.f,0.f,0.f};

  // ---- pipeline: phase p computes on buf p&1 while phase p+1 stages into buf ~(p&1)
  STAGE(0, W1s);                 // prologue
  __syncthreads();               // drain -> buf0 ready

  STAGE(1, W1s + 2048);          // issue phase 1
  MF(0, B[0], B[1]);             // phase 0: h0 @ W1c0
  __syncthreads();

  STAGE(0, W2s);                 // issue phase 2
  MF(1, B[2], B[3]);             // phase 1: h0 @ W1c1

  // epilogue B: bias+relu -> bf16 H-fragments via per-wave LDS regroup (hides W2c0 stage)
  const float4* b1v = (const float4*)b1;
  bf16x8 H[8];
  #pragma unroll
  for (int kkh = 0; kkh < 8; kkh++){
    char* tr = &trans[wv][kkh & 1][0];
    #pragma unroll
    for (int h = 0; h < 2; h++){
      int t = 2*kkh + h;
      float4 bb = b1v[t*4 + g];
      f32x4 a = acc[t];
      float v0 = fmaxf(a.x + bb.x, 0.f);
      float v1 = fmaxf(a.y + bb.y, 0.f);
      float v2 = fmaxf(a.z + bb.z, 0.f);
      float v3 = fmaxf(a.w + bb.w, 0.f);
      u32x2 dd; dd.x = pack2(v0, v1); dd.y = pack2(v2, v3);
      *(u32x2*)(tr + r*80 + h*32 + g*8) = dd;
    }
    H[kkh] = *(const bf16x8*)(tr + r*80 + g*16);
  }
  #pragma unroll
  for (int t = 0; t < 16; t++) acc[t] = (f32x4){0.f,0.f,0.f,0.f};
  __syncthreads();

  STAGE(1, W2s + 2048);          // issue phase 3
  MF(0, H[0], H[1]);             // phase 2: h1 @ W2c0
  __syncthreads();

  STAGE(0, W2s + 4096);          // issue phase 4
  MF(1, H[2], H[3]);             // phase 3: h1 @ W2c1
  __syncthreads();

  STAGE(1, W2s + 6144);          // issue phase 5
  MF(0, H[4], H[5]);             // phase 4: h1 @ W2c2
  __syncthreads();

  STAGE(0, Wps);                 // issue phase 6
  MF(1, H[6], H[7]);             // phase 5: h1 @ W2c3
  __syncthreads();

  STAGE(1, Wps + 2048);          // issue phase 7
  MF(0, XV[0], XV[1]);           // phase 6: x @ Wpc0
  __syncthreads();

  MF(1, XV[2], XV[3]);           // phase 7: x @ Wpc1

  if (tile0 < NT_){
    const float4* sc = (const float4*)scale;
    const float4* sh = (const float4*)shift;
    #pragma unroll
    for (int t = 0; t < 16; t++){
      float4 s = sc[t*4 + g], b = sh[t*4 + g];
      f32x4 a = acc[t];
      float4 o;
      o.x = fmaf(a.x, s.x, b.x);
      o.y = fmaf(a.y, s.y, b.y);
      o.z = fmaf(a.z, s.z, b.z);
      o.w = fmaf(a.w, s.w, b.w);
      *(float4*)(out + ((size_t)tile*16 + r)*OUTD_ + t*16 + g*4) = o;
    }
  }
}

extern "C" void kernel_launch(void* const* d_in, const int* in_sizes, int n_in,
                              void* d_out, int out_size, void* d_ws, size_t ws_size,
                              hipStream_t stream)
{
  const float* x     = (const float*)d_in[0];
  const int*   ei    = (const int*)d_in[1];     // [2][E]: src then dst
  const float* eps   = (const float*)d_in[2];
  const float* W1    = (const float*)d_in[3];
  const float* b1    = (const float*)d_in[4];
  const float* W2    = (const float*)d_in[5];
  const float* b2    = (const float*)d_in[6];
  const float* gamma = (const float*)d_in[7];
  const float* beta  = (const float*)d_in[8];
  const float* rmean = (const float*)d_in[9];
  const float* rvar  = (const float*)d_in[10];
  const float* Wp    = (const float*)d_in[11];
  const float* bp    = (const float*)d_in[12];
  float* out = (float*)d_out;

  char* ws = (char*)d_ws; size_t off = 0;
  auto carve = [&](size_t b)->char* { char* p = ws + off; off = (off + b + 255) & ~(size_t)255; return p; };
  unsigned*       xbuf  = (unsigned*)carve((size_t)CASTN_*4);   // x as bf16 pairs
  unsigned*       h0    = (unsigned*)carve((size_t)N_*64*4);    // h0 as bf16 pairs
  unsigned short* W1s   = (unsigned short*)carve(4096*16);
  unsigned short* W2s   = (unsigned short*)carve(8192*16);
  unsigned short* Wps   = (unsigned short*)carve(4096*16);
  float*          scale = (float*)carve(256*4);
  float*          shift = (float*)carve(256*4);
  int*            deg   = (int*)carve((size_t)N_*4);
  int*            cur   = (int*)carve((size_t)N_*4);
  int*            offs  = (int*)carve((size_t)(N_+1)*4);
  int*            adj   = (int*)carve((size_t)E_*4);
  int*            bsum  = (int*)carve((size_t)NB_*4);

  hipMemsetAsync(deg, 0, (size_t)N_*4, stream);
  hipMemsetAsync(cur, 0, (size_t)N_*4, stream);

  k_prep <<<(16640 + CASTN_ + E_ + 255)/256, 256, 0, stream>>>(x, W1, W2, Wp, b2, gamma, beta,
                                  rmean, rvar, bp, ei + E_, deg,
                                  W1s, W2s, Wps, scale, shift, xbuf);
  k_scan1<<<NB_, 1024, 0, stream>>>(deg, bsum, offs);
  k_scan2<<<NB_, 1024, 0, stream>>>(deg, bsum, offs);
  k_fill <<<(E_+255)/256, 256, 0, stream>>>(ei, ei + E_, offs, cur, adj);
  k_agg  <<<(N_+3)/4, 256, 0, stream>>>(xbuf, offs, adj, eps, h0);
  k_mlp  <<<(NT_+3)/4, 256, 0, stream>>>((const unsigned short*)h0, (const unsigned short*)xbuf,
                                         (const bf16x8*)W1s, b1, (const bf16x8*)W2s,
                                         (const bf16x8*)Wps, scale, shift, out);
}